// Round 9
// baseline (155.916 us; speedup 1.0000x reference)
//
#include <hip/hip_runtime.h>

#define B_ 8
#define EH_ 768
#define T_ 512
#define PH_ 320
#define U_ 128
#define JH_ 320
#define C_ 34
#define LDW 324          // W row stride in halfs (648 B = 2-bank step: conflict-free lrow reads)
#define EOFF2 (34 * LDW) // e region base (halfs); e rows unpadded (broadcast reads)

typedef _Float16 f16x8 __attribute__((ext_vector_type(8)));
typedef _Float16 f16x4 __attribute__((ext_vector_type(4)));
typedef float f32x4 __attribute__((ext_vector_type(4)));
typedef f32x4 f32x4u __attribute__((aligned(8)));   // 16B vector, 8B-aligned stores

// relu(a+b) on 8 packed halves: v_pk_add_f16 + v_pk_max_f16
static __device__ __forceinline__ f16x8 relu_sum8(f16x8 a, f16x8 b) {
    f16x8 s = a + b;
    f16x8 z = (f16x8)(_Float16)0.f;
    return __builtin_elementwise_max(s, z);
}

// ---------------------------------------------------------------------------
// Fused prep: transpose+cvt enc and dec (b,H,N)f32 -> (b,N,H)f16, cvt weights.
// ---------------------------------------------------------------------------
__global__ __launch_bounds__(256) void prep_kernel(
    const float* __restrict__ enc, const float* __restrict__ dec,
    const float* __restrict__ Wenc, const float* __restrict__ Wpred,
    const float* __restrict__ Wout,
    _Float16* __restrict__ enc_t, _Float16* __restrict__ dec_t,
    _Float16* __restrict__ wenc, _Float16* __restrict__ wpred,
    _Float16* __restrict__ wout)
{
    __shared__ _Float16 tile[32][36];
    const int NE = 16 * 24 * B_;
    const int ND = 4 * 10 * B_;
    const int tid = threadIdx.x;
    int bid = blockIdx.x;

    if (bid < NE + ND) {
        const float* src; _Float16* dst; int H, N, n0, h0, b;
        if (bid < NE) {
            src = enc; dst = enc_t; H = EH_; N = T_;
            n0 = (bid % 16) * 32; h0 = ((bid / 16) % 24) * 32; b = bid / (16 * 24);
        } else {
            int i = bid - NE;
            src = dec; dst = dec_t; H = PH_; N = U_;
            n0 = (i % 4) * 32; h0 = ((i / 4) % 10) * 32; b = i / 40;
        }
        const int tx = tid & 7, ty = tid >> 3;
        float4 v = *(const float4*)&src[((size_t)b * H + h0 + ty) * N + n0 + tx * 4];
        f16x4 t;
        t[0] = (_Float16)v.x; t[1] = (_Float16)v.y; t[2] = (_Float16)v.z; t[3] = (_Float16)v.w;
        *(f16x4*)&tile[ty][tx * 4] = t;
        __syncthreads();
        f16x4 o;
        o[0] = tile[tx * 4 + 0][ty];
        o[1] = tile[tx * 4 + 1][ty];
        o[2] = tile[tx * 4 + 2][ty];
        o[3] = tile[tx * 4 + 3][ty];
        *(f16x4*)&dst[((size_t)b * N + n0 + ty) * H + h0 + tx * 4] = o;
    } else {
        const int t1 = JH_ * EH_, t2 = JH_ * PH_, t3 = C_ * JH_;
        int i = (bid - NE - ND) * 256 + tid;
        if (i < t1)                wenc[i] = (_Float16)Wenc[i];
        else if (i < t1 + t2)      wpred[i - t1] = (_Float16)Wpred[i - t1];
        else if (i < t1 + t2 + t3) wout[i - t1 - t2] = (_Float16)Wout[i - t1 - t2];
    }
}

// ---------------------------------------------------------------------------
// Fused projections (e and p): dst[b,n,j] = bias[j] + sum_h src_t[b,n,h]*W[j,h]
// One wave = 16n x 32j tile (2 j-fragments share the af load), pure-register
// MFMA, no barriers. jt varies fastest (r3; neutral but harmless).
// ---------------------------------------------------------------------------
__global__ __launch_bounds__(256) void proj_kernel(
    const _Float16* __restrict__ enc_t, const _Float16* __restrict__ dec_t,
    const _Float16* __restrict__ wenc, const _Float16* __restrict__ wpred,
    const float* __restrict__ b_enc, const float* __restrict__ b_pred,
    _Float16* __restrict__ e_f, _Float16* __restrict__ p_f)
{
    const int tid = threadIdx.x;
    const int wave = tid >> 6, lane = tid & 63;
    const int lrow = lane & 15, quad = lane >> 4;

    int wid = blockIdx.x * 4 + wave;
    const int We = (T_ / 16) * (JH_ / 32) * B_;
    const _Float16 *src, *W; const float* bias; _Float16* dst; int H, N;
    if (wid < We) { src = enc_t; W = wenc;  bias = b_enc;  dst = e_f; H = EH_; N = T_; }
    else { wid -= We; src = dec_t; W = wpred; bias = b_pred; dst = p_f; H = PH_; N = U_; }

    const int njt = JH_ / 32;           // 10, both paths
    const int ntn = N / 16;
    const int jt = wid % njt; int r = wid / njt;
    const int nt = r % ntn; const int b = r / ntn;
    const int n0 = nt * 16, j0 = jt * 32;

    const _Float16* ap  = src + ((size_t)b * N + n0 + lrow) * H + quad * 8;
    const _Float16* wp0 = W + (size_t)(j0 + lrow) * H + quad * 8;
    const _Float16* wp1 = wp0 + (size_t)16 * H;

    f32x4 acc0 = {0.f, 0.f, 0.f, 0.f};
    f32x4 acc1 = {0.f, 0.f, 0.f, 0.f};
#pragma unroll 4
    for (int k = 0; k < H; k += 32) {
        f16x8 af = *(const f16x8*)(ap + k);
        f16x8 w0 = *(const f16x8*)(wp0 + k);
        f16x8 w1 = *(const f16x8*)(wp1 + k);
        acc0 = __builtin_amdgcn_mfma_f32_16x16x32_f16(w0, af, acc0, 0, 0, 0);
        acc1 = __builtin_amdgcn_mfma_f32_16x16x32_f16(w1, af, acc1, 0, 0, 0);
    }
    // D: row = j (quad*4+i), col = n (lane&15)
    const float4 bj0 = *(const float4*)&bias[j0 + quad * 4];
    const float4 bj1 = *(const float4*)&bias[j0 + 16 + quad * 4];
    f16x4 o0, o1;
    o0[0] = (_Float16)(acc0[0] + bj0.x);
    o0[1] = (_Float16)(acc0[1] + bj0.y);
    o0[2] = (_Float16)(acc0[2] + bj0.z);
    o0[3] = (_Float16)(acc0[3] + bj0.w);
    o1[0] = (_Float16)(acc1[0] + bj1.x);
    o1[1] = (_Float16)(acc1[1] + bj1.y);
    o1[2] = (_Float16)(acc1[2] + bj1.z);
    o1[3] = (_Float16)(acc1[3] + bj1.w);
    _Float16* dp = dst + ((size_t)b * N + n0 + lrow) * JH_ + j0;
    *(f16x4*)&dp[quad * 4]      = o0;
    *(f16x4*)&dp[16 + quad * 4] = o1;
}

// ---------------------------------------------------------------------------
// Fused joint: logits = relu(e[t]+p[u]) @ W_out^T + b_out, log_softmax (C=34)
// R9 RESTRUCTURE -- attack the register-bound occupancy (r4: 76 arch + 96
// acc-AGPR = 172 regs -> 2 waves/SIMD, Occ 22% measured; unified 512-reg file):
//   - grid (T/16, U/16, B) = 2048 blocks; block 256 = 4 waves; wave = 4t x 16u.
//   - acc[4][3] = 48 AGPR (half of before).
//   - p lives in REGISTERS: each lane pre-loads its u-row's 10 f16x8 frags
//     (40 VGPR) from global once -- identical data to the old LDS pv reads
//     (lane (lrow,quad) holds p[u0+lrow, quad*8+kk*32 ..+7]).
//   - LDS only W(34 rows @ LDW) + e(16 rows @ 320) = 32.3 KB -> 4 blocks/CU.
//   - kk loop FULLY UNROLLED (static pv[kk] indexing; also gives the
//     scheduler a straight-line body to pipeline LDS reads across kk).
//   - total regs ~120 <= 128 -> 4 waves/SIMD, 16 waves/CU (~50%, 2x r4).
// Loop reads/kk: w0,w1,w2 (per-lane lrow) + ev[0..3] (quad-broadcast) = 7.
// W's third MFMA fragment (rows 34..47) reads into the e region: garbage is
// confined to D-rows c>=34 which are never stored (D row = A row = c).
// Epilogue: no-max log_softmax (r6, verified), direct stores (r7 form).
// ---------------------------------------------------------------------------
__global__ __launch_bounds__(256, 4)
void joint_kernel(
    const _Float16* __restrict__ e_f, const _Float16* __restrict__ p_f,
    const _Float16* __restrict__ wout_f, const float* __restrict__ b_out,
    float* __restrict__ out)
{
    __shared__ alignas(16) _Float16 lds[34 * LDW + 16 * 320];   // 32.3 KB

    const int tid = threadIdx.x;
    const int t0 = blockIdx.x * 16;
    const int u0 = blockIdx.y * 16;
    const int b  = blockIdx.z;

    const int lane = tid & 63, wave = tid >> 6;
    const int lrow = lane & 15, quad = lane >> 4;
    const int lk = quad * 8;

    // ---- p -> registers (issued first; latency hides under LDS staging) ----
    const _Float16* pp = p_f + ((size_t)b * U_ + u0 + lrow) * JH_ + lk;
    f16x8 pv[10];
#pragma unroll
    for (int kk = 0; kk < 10; ++kk)
        pv[kk] = *(const f16x8*)(pp + kk * 32);

    // ---- stage W and e into LDS ----
    {
        const uint4* sw = (const uint4*)wout_f;
        for (int i = tid; i < 34 * 40; i += 256) {
            int rr = i / 40, k8 = i % 40;
            *(uint4*)&lds[rr * LDW + k8 * 8] = sw[i];
        }
        const uint4* se = (const uint4*)(e_f + ((size_t)b * T_ + t0) * JH_);
        for (int i = tid; i < 16 * 40; i += 256) {
            int rr = i / 40, k8 = i % 40;
            *(uint4*)&lds[EOFF2 + rr * 320 + k8 * 8] = se[i];
        }
    }
    __syncthreads();

    const int tbase = wave * 4;           // first e row for this wave

    f32x4 acc[4][3];
#pragma unroll
    for (int tt = 0; tt < 4; ++tt)
#pragma unroll
        for (int c = 0; c < 3; ++c) acc[tt][c] = (f32x4){0.f, 0.f, 0.f, 0.f};

#pragma unroll
    for (int kk = 0; kk < 10; ++kk) {
        const int k = lk + kk * 32;
        f16x8 w0 = *(const f16x8*)&lds[(0  + lrow) * LDW + k];
        f16x8 w1 = *(const f16x8*)&lds[(16 + lrow) * LDW + k];
        f16x8 w2 = *(const f16x8*)&lds[(32 + lrow) * LDW + k];   // rows>=34: garbage, confined
#pragma unroll
        for (int tt = 0; tt < 4; ++tt) {
            f16x8 ev = *(const f16x8*)&lds[EOFF2 + (tbase + tt) * 320 + k];
            f16x8 h = relu_sum8(pv[kk], ev);
            acc[tt][0] = __builtin_amdgcn_mfma_f32_16x16x32_f16(w0, h, acc[tt][0], 0, 0, 0);
            acc[tt][1] = __builtin_amdgcn_mfma_f32_16x16x32_f16(w1, h, acc[tt][1], 0, 0, 0);
            acc[tt][2] = __builtin_amdgcn_mfma_f32_16x16x32_f16(w2, h, acc[tt][2], 0, 0, 0);
        }
    }

    // D: row = c = frag*16 + quad*4 + i, col = u = lane&15.
    // log_softmax without max-subtraction (r6, verified): logits bounded.
    const f32x4 B0 = *(const f32x4*)&b_out[quad * 4];
    const f32x4 B1 = *(const f32x4*)&b_out[16 + quad * 4];
    const bool q0 = (quad == 0);
    const float b2x = q0 ? b_out[32] : 0.f;
    const float b2y = q0 ? b_out[33] : 0.f;

    float* pob = out + (((size_t)b * T_ + t0 + tbase) * U_ + u0 + lrow) * C_;
#pragma unroll
    for (int tt = 0; tt < 4; ++tt) {
        const f32x4 a0 = acc[tt][0] + B0;
        const f32x4 a1 = acc[tt][1] + B1;
        const float v2x = acc[tt][2][0] + b2x;
        const float v2y = acc[tt][2][1] + b2y;

        float s = __expf(a0[0]) + __expf(a0[1]) + __expf(a0[2]) + __expf(a0[3])
                + __expf(a1[0]) + __expf(a1[1]) + __expf(a1[2]) + __expf(a1[3]);
        if (q0) s += __expf(v2x) + __expf(v2y);
        s += __shfl_xor(s, 16);
        s += __shfl_xor(s, 32);
        const float lse = __logf(s);

        *(f32x4u*)&pob[quad * 4]      = a0 - lse;
        *(f32x4u*)&pob[16 + quad * 4] = a1 - lse;
        if (q0) *(float2*)&pob[32]    = make_float2(v2x - lse, v2y - lse);
        pob += U_ * C_;   // next t row
    }
}

extern "C" void kernel_launch(void* const* d_in, const int* in_sizes, int n_in,
                              void* d_out, int out_size, void* d_ws, size_t ws_size,
                              hipStream_t stream) {
    const float* enc    = (const float*)d_in[0];
    const float* dec    = (const float*)d_in[1];
    const float* W_enc  = (const float*)d_in[2];
    const float* b_enc  = (const float*)d_in[3];
    const float* W_pred = (const float*)d_in[4];
    const float* b_pred = (const float*)d_in[5];
    const float* W_out  = (const float*)d_in[6];
    const float* b_out  = (const float*)d_in[7];
    float* out = (float*)d_out;

    _Float16* enc_t  = (_Float16*)d_ws;                         // (B,T,EH)
    _Float16* dec_t  = enc_t  + (size_t)B_ * T_ * EH_;          // (B,U,PH)
    _Float16* wenc_f = dec_t  + (size_t)B_ * U_ * PH_;          // (JH,EH)
    _Float16* wpred_f= wenc_f + (size_t)JH_ * EH_;              // (JH,PH)
    _Float16* wout_f = wpred_f+ (size_t)JH_ * PH_;              // (34,JH)
    _Float16* e_f    = wout_f + (size_t)C_ * JH_;               // (B,T,JH)
    _Float16* p_f    = e_f    + (size_t)B_ * T_ * JH_;          // (B,U,JH)

    const int NE = 16 * 24 * B_, ND = 4 * 10 * B_;
    const int NW = (JH_ * EH_ + JH_ * PH_ + C_ * JH_ + 255) / 256;
    prep_kernel<<<dim3(NE + ND + NW), 256, 0, stream>>>(
        enc, dec, W_enc, W_pred, W_out, enc_t, dec_t, wenc_f, wpred_f, wout_f);

    const int We = (T_ / 16) * (JH_ / 32) * B_;
    const int Wp = (U_ / 16) * (JH_ / 32) * B_;
    proj_kernel<<<dim3((We + Wp) / 4), 256, 0, stream>>>(
        enc_t, dec_t, wenc_f, wpred_f, b_enc, b_pred, e_f, p_f);

    joint_kernel<<<dim3(T_ / 16, U_ / 16, B_), 256, 0, stream>>>(e_f, p_f, wout_f, b_out, out);
}

// Round 10
// 150.737 us; speedup vs baseline: 1.0344x; 1.0344x over previous
//
#include <hip/hip_runtime.h>

#define B_ 8
#define EH_ 768
#define T_ 512
#define PH_ 320
#define U_ 128
#define JH_ 320
#define C_ 34
#define LDW 324          // W/p row stride in halfs (648 B = 2-bank step: conflict-free lrow reads)
#define EOFF3 (50 * LDW) // e region base: after W(34) + p(16) rows

typedef _Float16 f16x8 __attribute__((ext_vector_type(8)));
typedef _Float16 f16x4 __attribute__((ext_vector_type(4)));
typedef float f32x4 __attribute__((ext_vector_type(4)));
typedef f32x4 f32x4u __attribute__((aligned(8)));   // 16B vector, 8B-aligned stores

// relu(a+b) on 8 packed halves: v_pk_add_f16 + v_pk_max_f16
static __device__ __forceinline__ f16x8 relu_sum8(f16x8 a, f16x8 b) {
    f16x8 s = a + b;
    f16x8 z = (f16x8)(_Float16)0.f;
    return __builtin_elementwise_max(s, z);
}

// ---------------------------------------------------------------------------
// Fused prep: transpose+cvt enc and dec (b,H,N)f32 -> (b,N,H)f16, cvt weights.
// ---------------------------------------------------------------------------
__global__ __launch_bounds__(256) void prep_kernel(
    const float* __restrict__ enc, const float* __restrict__ dec,
    const float* __restrict__ Wenc, const float* __restrict__ Wpred,
    const float* __restrict__ Wout,
    _Float16* __restrict__ enc_t, _Float16* __restrict__ dec_t,
    _Float16* __restrict__ wenc, _Float16* __restrict__ wpred,
    _Float16* __restrict__ wout)
{
    __shared__ _Float16 tile[32][36];
    const int NE = 16 * 24 * B_;
    const int ND = 4 * 10 * B_;
    const int tid = threadIdx.x;
    int bid = blockIdx.x;

    if (bid < NE + ND) {
        const float* src; _Float16* dst; int H, N, n0, h0, b;
        if (bid < NE) {
            src = enc; dst = enc_t; H = EH_; N = T_;
            n0 = (bid % 16) * 32; h0 = ((bid / 16) % 24) * 32; b = bid / (16 * 24);
        } else {
            int i = bid - NE;
            src = dec; dst = dec_t; H = PH_; N = U_;
            n0 = (i % 4) * 32; h0 = ((i / 4) % 10) * 32; b = i / 40;
        }
        const int tx = tid & 7, ty = tid >> 3;
        float4 v = *(const float4*)&src[((size_t)b * H + h0 + ty) * N + n0 + tx * 4];
        f16x4 t;
        t[0] = (_Float16)v.x; t[1] = (_Float16)v.y; t[2] = (_Float16)v.z; t[3] = (_Float16)v.w;
        *(f16x4*)&tile[ty][tx * 4] = t;
        __syncthreads();
        f16x4 o;
        o[0] = tile[tx * 4 + 0][ty];
        o[1] = tile[tx * 4 + 1][ty];
        o[2] = tile[tx * 4 + 2][ty];
        o[3] = tile[tx * 4 + 3][ty];
        *(f16x4*)&dst[((size_t)b * N + n0 + ty) * H + h0 + tx * 4] = o;
    } else {
        const int t1 = JH_ * EH_, t2 = JH_ * PH_, t3 = C_ * JH_;
        int i = (bid - NE - ND) * 256 + tid;
        if (i < t1)                wenc[i] = (_Float16)Wenc[i];
        else if (i < t1 + t2)      wpred[i - t1] = (_Float16)Wpred[i - t1];
        else if (i < t1 + t2 + t3) wout[i - t1 - t2] = (_Float16)Wout[i - t1 - t2];
    }
}

// ---------------------------------------------------------------------------
// Fused projections (e and p): dst[b,n,j] = bias[j] + sum_h src_t[b,n,h]*W[j,h]
// One wave = 16n x 32j tile (2 j-fragments share the af load), pure-register
// MFMA, no barriers. jt varies fastest (r3; neutral but harmless).
// ---------------------------------------------------------------------------
__global__ __launch_bounds__(256) void proj_kernel(
    const _Float16* __restrict__ enc_t, const _Float16* __restrict__ dec_t,
    const _Float16* __restrict__ wenc, const _Float16* __restrict__ wpred,
    const float* __restrict__ b_enc, const float* __restrict__ b_pred,
    _Float16* __restrict__ e_f, _Float16* __restrict__ p_f)
{
    const int tid = threadIdx.x;
    const int wave = tid >> 6, lane = tid & 63;
    const int lrow = lane & 15, quad = lane >> 4;

    int wid = blockIdx.x * 4 + wave;
    const int We = (T_ / 16) * (JH_ / 32) * B_;
    const _Float16 *src, *W; const float* bias; _Float16* dst; int H, N;
    if (wid < We) { src = enc_t; W = wenc;  bias = b_enc;  dst = e_f; H = EH_; N = T_; }
    else { wid -= We; src = dec_t; W = wpred; bias = b_pred; dst = p_f; H = PH_; N = U_; }

    const int njt = JH_ / 32;           // 10, both paths
    const int ntn = N / 16;
    const int jt = wid % njt; int r = wid / njt;
    const int nt = r % ntn; const int b = r / ntn;
    const int n0 = nt * 16, j0 = jt * 32;

    const _Float16* ap  = src + ((size_t)b * N + n0 + lrow) * H + quad * 8;
    const _Float16* wp0 = W + (size_t)(j0 + lrow) * H + quad * 8;
    const _Float16* wp1 = wp0 + (size_t)16 * H;

    f32x4 acc0 = {0.f, 0.f, 0.f, 0.f};
    f32x4 acc1 = {0.f, 0.f, 0.f, 0.f};
#pragma unroll 4
    for (int k = 0; k < H; k += 32) {
        f16x8 af = *(const f16x8*)(ap + k);
        f16x8 w0 = *(const f16x8*)(wp0 + k);
        f16x8 w1 = *(const f16x8*)(wp1 + k);
        acc0 = __builtin_amdgcn_mfma_f32_16x16x32_f16(w0, af, acc0, 0, 0, 0);
        acc1 = __builtin_amdgcn_mfma_f32_16x16x32_f16(w1, af, acc1, 0, 0, 0);
    }
    // D: row = j (quad*4+i), col = n (lane&15)
    const float4 bj0 = *(const float4*)&bias[j0 + quad * 4];
    const float4 bj1 = *(const float4*)&bias[j0 + 16 + quad * 4];
    f16x4 o0, o1;
    o0[0] = (_Float16)(acc0[0] + bj0.x);
    o0[1] = (_Float16)(acc0[1] + bj0.y);
    o0[2] = (_Float16)(acc0[2] + bj0.z);
    o0[3] = (_Float16)(acc0[3] + bj0.w);
    o1[0] = (_Float16)(acc1[0] + bj1.x);
    o1[1] = (_Float16)(acc1[1] + bj1.y);
    o1[2] = (_Float16)(acc1[2] + bj1.z);
    o1[3] = (_Float16)(acc1[3] + bj1.w);
    _Float16* dp = dst + ((size_t)b * N + n0 + lrow) * JH_ + j0;
    *(f16x4*)&dp[quad * 4]      = o0;
    *(f16x4*)&dp[16 + quad * 4] = o1;
}

// ---------------------------------------------------------------------------
// Fused joint: logits = relu(e[t]+p[u]) @ W_out^T + b_out, log_softmax (C=34)
// R10 = r9 structure, SPILL-FREE (r9's ord-0 dispatch ran 146us at 1.8%
// occupancy -- scratch lazy-alloc signature from the unrolled pv[10] body;
// steady-state dispatches were already < 45us):
//   - grid (T/16, U/16, B) = 2048 blocks; block 256 = 4 waves; wave = 4t x 16u;
//     acc[4][3] = 48 AGPR.
//   - p back in LDS (16 rows @ LDW after W): rolled kk loop, no register
//     array, no scratch. In-loop live set ~30 regs -> ~50 arch + 48 acc.
//   - LDS: W(34) + p(16) rows @ LDW=324 + e(16) rows @ 320 = 42.6 KB
//     -> 3 blocks/CU = 12 waves/CU (1.7x r4's measured 22%).
//   - reads/kk = 8 (pv, w0, w1, w2, ev[0..3]) for 12 MFMA.
// W's third MFMA fragment (rows 34..47) reads into the p region: garbage is
// confined to D-rows c>=34 which are never stored (D row = A row = c).
// Epilogue: no-max log_softmax (r6, verified), direct stores (r7 form).
// ---------------------------------------------------------------------------
__global__ __launch_bounds__(256)
void joint_kernel(
    const _Float16* __restrict__ e_f, const _Float16* __restrict__ p_f,
    const _Float16* __restrict__ wout_f, const float* __restrict__ b_out,
    float* __restrict__ out)
{
    __shared__ alignas(16) _Float16 lds[50 * LDW + 16 * 320];   // 42.6 KB

    const int tid = threadIdx.x;
    const int t0 = blockIdx.x * 16;
    const int u0 = blockIdx.y * 16;
    const int b  = blockIdx.z;

    // ---- stage W, p, e into LDS ----
    {
        const uint4* sw = (const uint4*)wout_f;
        for (int i = tid; i < 34 * 40; i += 256) {
            int rr = i / 40, k8 = i % 40;
            *(uint4*)&lds[rr * LDW + k8 * 8] = sw[i];
        }
        const uint4* sp = (const uint4*)(p_f + ((size_t)b * U_ + u0) * JH_);
        for (int i = tid; i < 16 * 40; i += 256) {
            int rr = i / 40, k8 = i % 40;
            *(uint4*)&lds[(34 + rr) * LDW + k8 * 8] = sp[i];
        }
        const uint4* se = (const uint4*)(e_f + ((size_t)b * T_ + t0) * JH_);
        for (int i = tid; i < 16 * 40; i += 256) {
            int rr = i / 40, k8 = i % 40;
            *(uint4*)&lds[EOFF3 + rr * 320 + k8 * 8] = se[i];
        }
    }
    __syncthreads();

    const int lane = tid & 63, wave = tid >> 6;
    const int lrow = lane & 15, quad = lane >> 4;
    const int lk = quad * 8;
    const int urow  = 34 + lrow;          // p row in LDS
    const int tbase = wave * 4;           // first e row for this wave

    f32x4 acc[4][3];
#pragma unroll
    for (int tt = 0; tt < 4; ++tt)
#pragma unroll
        for (int c = 0; c < 3; ++c) acc[tt][c] = (f32x4){0.f, 0.f, 0.f, 0.f};

    for (int kk = 0; kk < 10; ++kk) {
        const int k = lk + kk * 32;
        f16x8 pv = *(const f16x8*)&lds[urow * LDW + k];
        f16x8 w0 = *(const f16x8*)&lds[(0  + lrow) * LDW + k];
        f16x8 w1 = *(const f16x8*)&lds[(16 + lrow) * LDW + k];
        f16x8 w2 = *(const f16x8*)&lds[(32 + lrow) * LDW + k];   // rows>=34: garbage, confined
#pragma unroll
        for (int tt = 0; tt < 4; ++tt) {
            f16x8 ev = *(const f16x8*)&lds[EOFF3 + (tbase + tt) * 320 + k];
            f16x8 h = relu_sum8(pv, ev);
            acc[tt][0] = __builtin_amdgcn_mfma_f32_16x16x32_f16(w0, h, acc[tt][0], 0, 0, 0);
            acc[tt][1] = __builtin_amdgcn_mfma_f32_16x16x32_f16(w1, h, acc[tt][1], 0, 0, 0);
            acc[tt][2] = __builtin_amdgcn_mfma_f32_16x16x32_f16(w2, h, acc[tt][2], 0, 0, 0);
        }
    }

    // D: row = c = frag*16 + quad*4 + i, col = u = lane&15.
    // log_softmax without max-subtraction (r6, verified): logits bounded.
    const f32x4 B0 = *(const f32x4*)&b_out[quad * 4];
    const f32x4 B1 = *(const f32x4*)&b_out[16 + quad * 4];
    const bool q0 = (quad == 0);
    const float b2x = q0 ? b_out[32] : 0.f;
    const float b2y = q0 ? b_out[33] : 0.f;

    float* pob = out + (((size_t)b * T_ + t0 + tbase) * U_ + u0 + lrow) * C_;
#pragma unroll
    for (int tt = 0; tt < 4; ++tt) {
        const f32x4 a0 = acc[tt][0] + B0;
        const f32x4 a1 = acc[tt][1] + B1;
        const float v2x = acc[tt][2][0] + b2x;
        const float v2y = acc[tt][2][1] + b2y;

        float s = __expf(a0[0]) + __expf(a0[1]) + __expf(a0[2]) + __expf(a0[3])
                + __expf(a1[0]) + __expf(a1[1]) + __expf(a1[2]) + __expf(a1[3]);
        if (q0) s += __expf(v2x) + __expf(v2y);
        s += __shfl_xor(s, 16);
        s += __shfl_xor(s, 32);
        const float lse = __logf(s);

        *(f32x4u*)&pob[quad * 4]      = a0 - lse;
        *(f32x4u*)&pob[16 + quad * 4] = a1 - lse;
        if (q0) *(float2*)&pob[32]    = make_float2(v2x - lse, v2y - lse);
        pob += U_ * C_;   // next t row
    }
}

extern "C" void kernel_launch(void* const* d_in, const int* in_sizes, int n_in,
                              void* d_out, int out_size, void* d_ws, size_t ws_size,
                              hipStream_t stream) {
    const float* enc    = (const float*)d_in[0];
    const float* dec    = (const float*)d_in[1];
    const float* W_enc  = (const float*)d_in[2];
    const float* b_enc  = (const float*)d_in[3];
    const float* W_pred = (const float*)d_in[4];
    const float* b_pred = (const float*)d_in[5];
    const float* W_out  = (const float*)d_in[6];
    const float* b_out  = (const float*)d_in[7];
    float* out = (float*)d_out;

    _Float16* enc_t  = (_Float16*)d_ws;                         // (B,T,EH)
    _Float16* dec_t  = enc_t  + (size_t)B_ * T_ * EH_;          // (B,U,PH)
    _Float16* wenc_f = dec_t  + (size_t)B_ * U_ * PH_;          // (JH,EH)
    _Float16* wpred_f= wenc_f + (size_t)JH_ * EH_;              // (JH,PH)
    _Float16* wout_f = wpred_f+ (size_t)JH_ * PH_;              // (34,JH)
    _Float16* e_f    = wout_f + (size_t)C_ * JH_;               // (B,T,JH)
    _Float16* p_f    = e_f    + (size_t)B_ * T_ * JH_;          // (B,U,JH)

    const int NE = 16 * 24 * B_, ND = 4 * 10 * B_;
    const int NW = (JH_ * EH_ + JH_ * PH_ + C_ * JH_ + 255) / 256;
    prep_kernel<<<dim3(NE + ND + NW), 256, 0, stream>>>(
        enc, dec, W_enc, W_pred, W_out, enc_t, dec_t, wenc_f, wpred_f, wout_f);

    const int We = (T_ / 16) * (JH_ / 32) * B_;
    const int Wp = (U_ / 16) * (JH_ / 32) * B_;
    proj_kernel<<<dim3((We + Wp) / 4), 256, 0, stream>>>(
        enc_t, dec_t, wenc_f, wpred_f, b_enc, b_pred, e_f, p_f);

    joint_kernel<<<dim3(T_ / 16, U_ / 16, B_), 256, 0, stream>>>(e_f, p_f, wout_f, b_out, out);
}